// Round 12
// baseline (1994.622 us; speedup 1.0000x reference)
//
#include <hip/hip_runtime.h>

#define HID  256
#define TT   2048
#define NB   128
#define NTHR 1024

// DPP-based add of a rotated/broadcast copy (VALU pipe, no LDS traffic).
template <int CTRL>
__device__ __forceinline__ float dpp_add(float v) {
    int t = __builtin_amdgcn_update_dpp(0, __float_as_int(v), CTRL, 0xF, 0xF, true);
    return v + __int_as_float(t);
}

__device__ __forceinline__ float tanh_fast(float x) {
    float e = __expf(2.0f * x);
    float r = __builtin_amdgcn_rcpf(e + 1.0f);
    return fmaf(-2.0f, r, 1.0f);
}

// ---- prep: pack W_hh fp32 -> fp16 pairs in the exact per-thread chunk
// layout the main kernel loads (wave-coalesced uint4 chunks).
// u32 j = (((wv*8 + i)*64 + lane)*4 + k); thread tid=wv*64+lane owns
// rows 4*(tid>>4)+(i>>1), cols 16*(tid&15)+8*(i&1)+2k (+0 lo, +1 hi).
__global__ void pack_w(const float* __restrict__ W, unsigned int* __restrict__ out) {
    int j    = blockIdx.x * 256 + threadIdx.x;   // 0..32767
    int k    = j & 3;
    int lane = (j >> 2) & 63;
    int i    = (j >> 8) & 7;
    int wv   = j >> 11;
    int tid  = wv * 64 + lane;
    int row  = 4 * (tid >> 4) + (i >> 1);
    int col  = 16 * (tid & 15) + 8 * (i & 1) + 2 * k;
    _Float16 lo = (_Float16)W[row * HID + col];
    _Float16 hi = (_Float16)W[row * HID + col + 1];
    unsigned short ulo, uhi;
    __builtin_memcpy(&ulo, &lo, 2);
    __builtin_memcpy(&uhi, &hi, 2);
    out[j] = (unsigned int)ulo | ((unsigned int)uhi << 16);
}

// v_fma_mix_f32: D.f32 = A*B + C with per-operand f16/f32 mixing.
// op_sel_hi:[1,0,0] -> A is f16 (lo16 unless op_sel[0]=1 -> hi16), B,C f32.
#define MIXLO(ACC, W, H) asm("v_fma_mix_f32 %0, %1, %2, %0 op_sel_hi:[1,0,0]" \
                             : "+v"(ACC) : "v"(W), "v"(H))
#define MIXHI(ACC, W, H) asm("v_fma_mix_f32 %0, %1, %2, %0 op_sel:[1,0,0] op_sel_hi:[1,0,0]" \
                             : "+v"(ACC) : "v"(W), "v"(H))

#define DECL_CH(C) unsigned int Wc##C##_0, Wc##C##_1, Wc##C##_2, Wc##C##_3;
#define LOAD_CH(C) do { \
    uint4 t_ = wq[(wv * 8 + C) * 64 + lane]; \
    Wc##C##_0 = t_.x; Wc##C##_1 = t_.y; Wc##C##_2 = t_.z; Wc##C##_3 = t_.w; \
} while (0)

// chunk C covers 8 consecutive h values H0..H7 (cols 8*(C&1)..+7 of this
// thread's 16-col slice); u32 k packs (col 2k lo, col 2k+1 hi).
#define FMA_CH(ACC, C, H0, H1, H2, H3, H4, H5, H6, H7) do { \
    MIXLO(ACC, Wc##C##_0, H0); MIXHI(ACC, Wc##C##_0, H1); \
    MIXLO(ACC, Wc##C##_1, H2); MIXHI(ACC, Wc##C##_1, H3); \
    MIXLO(ACC, Wc##C##_2, H4); MIXHI(ACC, Wc##C##_2, H5); \
    MIXLO(ACC, Wc##C##_3, H6); MIXHI(ACC, Wc##C##_3, H7); \
} while (0)

#define PIN16(A0,A1,A2,A3,A4,A5,A6,A7,A8,A9,Aa,Ab,Ac,Ad,Ae,Af) \
    asm volatile("" : "+v"(A0), "+v"(A1), "+v"(A2), "+v"(A3), \
                      "+v"(A4), "+v"(A5), "+v"(A6), "+v"(A7), \
                      "+v"(A8), "+v"(A9), "+v"(Aa), "+v"(Ab), \
                      "+v"(Ac), "+v"(Ad), "+v"(Ae), "+v"(Af))

#define RED16(A) do { \
    A = dpp_add<0xB1>(A); A = dpp_add<0x4E>(A); \
    A = dpp_add<0x124>(A); A = dpp_add<0x128>(A); \
} while (0)

// fp16 pivot (round 12): weights as 32 packed-fp16 u32 per thread, consumed
// directly by v_fma_mix_f32 (fp32 accumulate). Hedged: resident -> VALU/LDS
// floor ~900cyc/step; streamed -> L2 floor ~875cyc/step (half of fp32's
// 1780). LDS clamp retained (1 block/CU -> 128-VGPR budget); in-loop pins
// retained (spill-cost ranking).
__global__ __launch_bounds__(NTHR)
void rnn_persist(
    const float* __restrict__ x,      // [B, T, 1]
    const float* __restrict__ W_ih,   // [256, 1]
    const uint4* __restrict__ wq,     // packed fp16 W_hh (d_ws)
    const float* __restrict__ b_ih,   // [256]
    const float* __restrict__ b_hh,   // [256]
    const float* __restrict__ W_out,  // [1, 256]
    const float* __restrict__ b_out,  // [1]
    float* __restrict__ y)            // [B, T, 1]
{
    __shared__ __align__(16) float s_h[2][8 * 36];
    __shared__ float s_x[TT];
    __shared__ float s_part[2][16];
    // occupancy clamp: 1 block/CU -> 4 waves/SIMD -> RA VGPR budget 128
    __shared__ float s_pad[22528];   // 88 KB

    const int tid  = threadIdx.x;
    const int c3   = tid & 15;
    const int rg   = tid >> 4;
    const int lane = tid & 63;
    const int wv   = tid >> 6;
    const int b    = blockIdx.x;

    // keep s_pad alive (volatile access on unprovable-false path)
    if (b == -1) {
        volatile float* vp = s_pad;
        vp[tid] = 1.0f;
        y[tid] = vp[tid];
    }

    for (int k = tid; k < TT; k += NTHR) s_x[k] = x[(size_t)b * TT + k];

    DECL_CH(0) DECL_CH(1) DECL_CH(2) DECL_CH(3)
    DECL_CH(4) DECL_CH(5) DECL_CH(6) DECL_CH(7)
    LOAD_CH(0); LOAD_CH(1); LOAD_CH(2); LOAD_CH(3);
    LOAD_CH(4); LOAD_CH(5); LOAD_CH(6); LOAD_CH(7);

    const int   myrow = 4 * rg + (c3 & 3);
    const float wih   = W_ih[myrow];
    const float bias  = b_ih[myrow] + b_hh[myrow];
    const float wo_my = W_out[myrow];
    const float bout  = b_out[0];

    if (tid < 256) {
        int wd = 36 * (tid >> 5) + (tid & 31);
        s_h[0][wd] = 0.0f;
        s_h[1][wd] = 0.0f;
    }
    __syncthreads();

    int p = 0;
    float* yrow = y + (size_t)b * TT;
    const int hwword = 36 * (myrow >> 5) + (myrow & 31);
    const int rdbase = 36 * (c3 >> 1) + 16 * (c3 & 1);

    for (int step = 0; step <= TT; ++step) {
        // finalize y_{step-1}: rotating wave sums the 16 per-wave partials
        if (step >= 1 && wv == ((step - 1) & 15)) {
            float pp = s_part[(step - 1) & 1][lane & 15];
            pp = dpp_add<0xB1>(pp);
            pp = dpp_add<0x4E>(pp);
            pp = dpp_add<0x124>(pp);
            pp = dpp_add<0x128>(pp);
            if (lane == 0) yrow[step - 1] = pp + bout;
        }
        if (step == TT) break;

        // in-loop pins: weights must be in VGPRs here each iteration
        PIN16(Wc0_0, Wc0_1, Wc0_2, Wc0_3, Wc1_0, Wc1_1, Wc1_2, Wc1_3,
              Wc2_0, Wc2_1, Wc2_2, Wc2_3, Wc3_0, Wc3_1, Wc3_2, Wc3_3);
        PIN16(Wc4_0, Wc4_1, Wc4_2, Wc4_3, Wc5_0, Wc5_1, Wc5_2, Wc5_3,
              Wc6_0, Wc6_1, Wc6_2, Wc6_3, Wc7_0, Wc7_1, Wc7_2, Wc7_3);

        const float xt = s_x[step];
        const float* hb = &s_h[p][rdbase];
        const float4 H0 = *(const float4*)(hb);
        const float4 H1 = *(const float4*)(hb + 4);
        const float4 H2 = *(const float4*)(hb + 8);
        const float4 H3 = *(const float4*)(hb + 12);
        const float hx0 = H0.x, hx1 = H0.y, hx2  = H0.z, hx3  = H0.w;
        const float hx4 = H1.x, hx5 = H1.y, hx6  = H1.z, hx7  = H1.w;
        const float hx8 = H2.x, hx9 = H2.y, hx10 = H2.z, hx11 = H2.w;
        const float hx12 = H3.x, hx13 = H3.y, hx14 = H3.z, hx15 = H3.w;

        float acc0 = 0.0f, acc1 = 0.0f, acc2 = 0.0f, acc3 = 0.0f;
        // row r <- chunks 2r (h0..7) and 2r+1 (h8..15)
        FMA_CH(acc0, 0, hx0, hx1, hx2, hx3, hx4, hx5, hx6, hx7);
        FMA_CH(acc0, 1, hx8, hx9, hx10, hx11, hx12, hx13, hx14, hx15);
        FMA_CH(acc1, 2, hx0, hx1, hx2, hx3, hx4, hx5, hx6, hx7);
        FMA_CH(acc1, 3, hx8, hx9, hx10, hx11, hx12, hx13, hx14, hx15);
        FMA_CH(acc2, 4, hx0, hx1, hx2, hx3, hx4, hx5, hx6, hx7);
        FMA_CH(acc2, 5, hx8, hx9, hx10, hx11, hx12, hx13, hx14, hx15);
        FMA_CH(acc3, 6, hx0, hx1, hx2, hx3, hx4, hx5, hx6, hx7);
        FMA_CH(acc3, 7, hx8, hx9, hx10, hx11, hx12, hx13, hx14, hx15);

        RED16(acc0); RED16(acc1); RED16(acc2); RED16(acc3);

        float s01 = (c3 & 1) ? acc1 : acc0;
        float s23 = (c3 & 1) ? acc3 : acc2;
        float dot = (c3 & 2) ? s23 : s01;
        float hn  = tanh_fast(fmaf(xt, wih, bias) + dot);

        if ((c3 & 12) == 0) s_h[p ^ 1][hwword] = hn;   // c3 < 4

        float pv = ((c3 & 12) == 0) ? hn * wo_my : 0.0f;
        pv = dpp_add<0xB1>(pv);
        pv = dpp_add<0x4E>(pv);
        pv = dpp_add<0x124>(pv);
        pv = dpp_add<0x128>(pv);
        pv = dpp_add<0x142>(pv);   // row_bcast15
        pv = dpp_add<0x143>(pv);   // row_bcast31 -> lane63 holds full sum
        if (lane == 63) s_part[step & 1][wv] = pv;

        __syncthreads();
        p ^= 1;
    }
}

extern "C" void kernel_launch(void* const* d_in, const int* in_sizes, int n_in,
                              void* d_out, int out_size, void* d_ws, size_t ws_size,
                              hipStream_t stream) {
    const float* x     = (const float*)d_in[0];
    const float* W_ih  = (const float*)d_in[1];
    const float* W_hh  = (const float*)d_in[2];
    const float* b_ih  = (const float*)d_in[3];
    const float* b_hh  = (const float*)d_in[4];
    const float* W_out = (const float*)d_in[5];
    const float* b_out = (const float*)d_in[6];
    float* y = (float*)d_out;
    unsigned int* wpk = (unsigned int*)d_ws;   // 32768 u32 = 128 KB

    hipLaunchKernelGGL(pack_w, dim3(128), dim3(256), 0, stream, W_hh, wpk);
    hipLaunchKernelGGL(rnn_persist, dim3(NB), dim3(NTHR), 0, stream,
                       x, W_ih, (const uint4*)wpk, b_ih, b_hh, W_out, b_out, y);
}

// Round 13
// 1502.414 us; speedup vs baseline: 1.3276x; 1.3276x over previous
//
#include <hip/hip_runtime.h>
#include <hip/hip_fp16.h>

#define HID  256
#define TT   2048
#define NB   128
#define NTHR 1024

// DPP-based add of a rotated/broadcast copy (VALU pipe, no LDS traffic).
template <int CTRL>
__device__ __forceinline__ float dpp_add(float v) {
    int t = __builtin_amdgcn_update_dpp(0, __float_as_int(v), CTRL, 0xF, 0xF, true);
    return v + __int_as_float(t);
}

__device__ __forceinline__ float tanh_fast(float x) {
    float e = __expf(2.0f * x);
    float r = __builtin_amdgcn_rcpf(e + 1.0f);
    return fmaf(-2.0f, r, 1.0f);
}

__device__ __forceinline__ __half2 bc_h2(unsigned int u) {
    __half2 h;
    __builtin_memcpy(&h, &u, 4);
    return h;
}

// ---- prep: pack W_hh fp32 -> fp16 pairs, wave-coalesced uint4 chunks.
// u32 j = (((wv*8 + i)*64 + lane)*4 + k); thread tid=wv*64+lane owns
// rows 4*(tid>>4)+(i>>1), cols 16*(tid&15)+8*(i&1)+2k (+0 lo, +1 hi).
__global__ void pack_w(const float* __restrict__ W, unsigned int* __restrict__ out) {
    int j    = blockIdx.x * 256 + threadIdx.x;   // 0..32767
    int k    = j & 3;
    int lane = (j >> 2) & 63;
    int i    = (j >> 8) & 7;
    int wv   = j >> 11;
    int tid  = wv * 64 + lane;
    int row  = 4 * (tid >> 4) + (i >> 1);
    int col  = 16 * (tid & 15) + 8 * (i & 1) + 2 * k;
    _Float16 lo = (_Float16)W[row * HID + col];
    _Float16 hi = (_Float16)W[row * HID + col + 1];
    unsigned short ulo, uhi;
    __builtin_memcpy(&ulo, &lo, 2);
    __builtin_memcpy(&uhi, &hi, 2);
    out[j] = (unsigned int)ulo | ((unsigned int)uhi << 16);
}

// chunk T covers 8 consecutive h values H0..H7; u32 packs (lo=col 2k, hi=2k+1).
// Plain fmaf((float)half, f32, f32) -> LLVM forms v_fma_mix_f32 (f32 accum).
#define FMA_CH2(ACC, T, H0, H1, H2, H3, H4, H5, H6, H7) do { \
    __half2 a_ = bc_h2((T).x), b_ = bc_h2((T).y), c_ = bc_h2((T).z), d_ = bc_h2((T).w); \
    ACC = fmaf(__low2float(a_),  H0, ACC); ACC = fmaf(__high2float(a_), H1, ACC); \
    ACC = fmaf(__low2float(b_),  H2, ACC); ACC = fmaf(__high2float(b_), H3, ACC); \
    ACC = fmaf(__low2float(c_),  H4, ACC); ACC = fmaf(__high2float(c_), H5, ACC); \
    ACC = fmaf(__low2float(d_),  H6, ACC); ACC = fmaf(__high2float(d_), H7, ACC); \
} while (0)

#define RED16(A) do { \
    A = dpp_add<0xB1>(A); A = dpp_add<0x4E>(A); \
    A = dpp_add<0x124>(A); A = dpp_add<0x128>(A); \
} while (0)

// Round 13: stop fighting the register allocator (8 failed pin/clamp schemes,
// r2-r12 log in repo history). Let the compiler choose how to deliver the
// fp16 weights -- plain in-loop loads, no pins, no volatile, no asm. r2
// proved the compiler streams such loads from L2 at ~146 B/cyc/CU with deep
// pipelining; fp16 halves the bytes -> ~875 cyc/step floor. If it instead
// keeps the 32 u32 resident (pressure ~85 < 128 budget from LDS clamp),
// better still. All outcomes beat the fp32 floor of ~1780 cyc/step.
__global__ __launch_bounds__(NTHR)
void rnn_persist(
    const float* __restrict__ x,      // [B, T, 1]
    const float* __restrict__ W_ih,   // [256, 1]
    const uint4* __restrict__ wq,     // packed fp16 W_hh (d_ws)
    const float* __restrict__ b_ih,   // [256]
    const float* __restrict__ b_hh,   // [256]
    const float* __restrict__ W_out,  // [1, 256]
    const float* __restrict__ b_out,  // [1]
    float* __restrict__ y)            // [B, T, 1]
{
    __shared__ __align__(16) float s_h[2][8 * 36];
    __shared__ float s_x[TT];
    __shared__ float s_part[2][16];
    // occupancy clamp: 1 block/CU -> 4 waves/SIMD -> RA VGPR budget 128
    __shared__ float s_pad[22528];   // 88 KB

    const int tid  = threadIdx.x;
    const int c3   = tid & 15;
    const int rg   = tid >> 4;
    const int lane = tid & 63;
    const int wv   = tid >> 6;
    const int b    = blockIdx.x;

    // keep s_pad alive (volatile access on unprovable-false path)
    if (b == -1) {
        volatile float* vp = s_pad;
        vp[tid] = 1.0f;
        y[tid] = vp[tid];
    }

    for (int k = tid; k < TT; k += NTHR) s_x[k] = x[(size_t)b * TT + k];

    const uint4* wbase = wq + (size_t)wv * 8 * 64 + lane;

    const int   myrow = 4 * rg + (c3 & 3);
    const float wih   = W_ih[myrow];
    const float bias  = b_ih[myrow] + b_hh[myrow];
    const float wo_my = W_out[myrow];
    const float bout  = b_out[0];

    if (tid < 256) {
        int wd = 36 * (tid >> 5) + (tid & 31);
        s_h[0][wd] = 0.0f;
        s_h[1][wd] = 0.0f;
    }
    __syncthreads();

    int p = 0;
    float* yrow = y + (size_t)b * TT;
    const int hwword = 36 * (myrow >> 5) + (myrow & 31);
    const int rdbase = 36 * (c3 >> 1) + 16 * (c3 & 1);

    for (int step = 0; step <= TT; ++step) {
        // finalize y_{step-1}: rotating wave sums the 16 per-wave partials
        if (step >= 1 && wv == ((step - 1) & 15)) {
            float pp = s_part[(step - 1) & 1][lane & 15];
            pp = dpp_add<0xB1>(pp);
            pp = dpp_add<0x4E>(pp);
            pp = dpp_add<0x124>(pp);
            pp = dpp_add<0x128>(pp);
            if (lane == 0) yrow[step - 1] = pp + bout;
        }
        if (step == TT) break;

        // weights: plain loads, compiler-scheduled (stream or keep -- its call)
        const uint4 T0 = wbase[0 * 64];
        const uint4 T1 = wbase[1 * 64];
        const uint4 T2 = wbase[2 * 64];
        const uint4 T3 = wbase[3 * 64];
        const uint4 T4 = wbase[4 * 64];
        const uint4 T5 = wbase[5 * 64];
        const uint4 T6 = wbase[6 * 64];
        const uint4 T7 = wbase[7 * 64];

        const float xt = s_x[step];
        const float* hb = &s_h[p][rdbase];
        const float4 H0 = *(const float4*)(hb);
        const float4 H1 = *(const float4*)(hb + 4);
        const float4 H2 = *(const float4*)(hb + 8);
        const float4 H3 = *(const float4*)(hb + 12);
        const float hx0 = H0.x, hx1 = H0.y, hx2  = H0.z, hx3  = H0.w;
        const float hx4 = H1.x, hx5 = H1.y, hx6  = H1.z, hx7  = H1.w;
        const float hx8 = H2.x, hx9 = H2.y, hx10 = H2.z, hx11 = H2.w;
        const float hx12 = H3.x, hx13 = H3.y, hx14 = H3.z, hx15 = H3.w;

        float acc0 = 0.0f, acc1 = 0.0f, acc2 = 0.0f, acc3 = 0.0f;
        // row r <- chunks 2r (h0..7) and 2r+1 (h8..15)
        FMA_CH2(acc0, T0, hx0, hx1, hx2, hx3, hx4, hx5, hx6, hx7);
        FMA_CH2(acc0, T1, hx8, hx9, hx10, hx11, hx12, hx13, hx14, hx15);
        FMA_CH2(acc1, T2, hx0, hx1, hx2, hx3, hx4, hx5, hx6, hx7);
        FMA_CH2(acc1, T3, hx8, hx9, hx10, hx11, hx12, hx13, hx14, hx15);
        FMA_CH2(acc2, T4, hx0, hx1, hx2, hx3, hx4, hx5, hx6, hx7);
        FMA_CH2(acc2, T5, hx8, hx9, hx10, hx11, hx12, hx13, hx14, hx15);
        FMA_CH2(acc3, T6, hx0, hx1, hx2, hx3, hx4, hx5, hx6, hx7);
        FMA_CH2(acc3, T7, hx8, hx9, hx10, hx11, hx12, hx13, hx14, hx15);

        RED16(acc0); RED16(acc1); RED16(acc2); RED16(acc3);

        float s01 = (c3 & 1) ? acc1 : acc0;
        float s23 = (c3 & 1) ? acc3 : acc2;
        float dot = (c3 & 2) ? s23 : s01;
        float hn  = tanh_fast(fmaf(xt, wih, bias) + dot);

        if ((c3 & 12) == 0) s_h[p ^ 1][hwword] = hn;   // c3 < 4

        float pv = ((c3 & 12) == 0) ? hn * wo_my : 0.0f;
        pv = dpp_add<0xB1>(pv);
        pv = dpp_add<0x4E>(pv);
        pv = dpp_add<0x124>(pv);
        pv = dpp_add<0x128>(pv);
        pv = dpp_add<0x142>(pv);   // row_bcast15
        pv = dpp_add<0x143>(pv);   // row_bcast31 -> lane63 holds full sum
        if (lane == 63) s_part[step & 1][wv] = pv;

        __syncthreads();
        p ^= 1;
    }
}

extern "C" void kernel_launch(void* const* d_in, const int* in_sizes, int n_in,
                              void* d_out, int out_size, void* d_ws, size_t ws_size,
                              hipStream_t stream) {
    const float* x     = (const float*)d_in[0];
    const float* W_ih  = (const float*)d_in[1];
    const float* W_hh  = (const float*)d_in[2];
    const float* b_ih  = (const float*)d_in[3];
    const float* b_hh  = (const float*)d_in[4];
    const float* W_out = (const float*)d_in[5];
    const float* b_out = (const float*)d_in[6];
    float* y = (float*)d_out;
    unsigned int* wpk = (unsigned int*)d_ws;   // 32768 u32 = 128 KB

    hipLaunchKernelGGL(pack_w, dim3(128), dim3(256), 0, stream, W_hh, wpk);
    hipLaunchKernelGGL(rnn_persist, dim3(NB), dim3(NTHR), 0, stream,
                       x, W_ih, (const uint4*)wpk, b_ih, b_hh, W_out, b_out, y);
}

// Round 14
// 1478.313 us; speedup vs baseline: 1.3493x; 1.0163x over previous
//
#include <hip/hip_runtime.h>
#include <hip/hip_fp16.h>

#define HID  256
#define TT   2048
#define NB   128
#define NTHR 1024

typedef _Float16 hf2 __attribute__((ext_vector_type(2)));

template <int CTRL>
__device__ __forceinline__ float dpp_add(float v) {
    int t = __builtin_amdgcn_update_dpp(0, __float_as_int(v), CTRL, 0xF, 0xF, true);
    return v + __int_as_float(t);
}

__device__ __forceinline__ float tanh_fast(float x) {
    float e = __expf(2.0f * x);
    float r = __builtin_amdgcn_rcpf(e + 1.0f);
    return fmaf(-2.0f, r, 1.0f);
}

__device__ __forceinline__ hf2 bc2(unsigned int u) {
    hf2 h;
    __builtin_memcpy(&h, &u, 4);
    return h;
}

// ---- prep: pack W_hh fp32 -> fp16 pairs, wave-coalesced uint4 chunks.
// u32 j = (((wv*8 + i)*64 + lane)*4 + k); thread tid=wv*64+lane owns
// rows 4*(tid>>4)+(i>>1), cols 16*(tid&15)+8*(i&1)+2k (+0 lo, +1 hi).
__global__ void pack_w(const float* __restrict__ W, unsigned int* __restrict__ out) {
    int j    = blockIdx.x * 256 + threadIdx.x;   // 0..32767
    int k    = j & 3;
    int lane = (j >> 2) & 63;
    int i    = (j >> 8) & 7;
    int wv   = j >> 11;
    int tid  = wv * 64 + lane;
    int row  = 4 * (tid >> 4) + (i >> 1);
    int col  = 16 * (tid & 15) + 8 * (i & 1) + 2 * k;
    _Float16 lo = (_Float16)W[row * HID + col];
    _Float16 hi = (_Float16)W[row * HID + col + 1];
    unsigned short ulo, uhi;
    __builtin_memcpy(&ulo, &lo, 2);
    __builtin_memcpy(&uhi, &hi, 2);
    out[j] = (unsigned int)ulo | ((unsigned int)uhi << 16);
}

// 4 x v_dot2_f32_f16: 8 MACs, f32 accumulate
#define DOT4(ACC, Tv, Hv) do { \
    ACC = __builtin_amdgcn_fdot2(bc2((Tv).x), bc2((Hv).x), ACC, false); \
    ACC = __builtin_amdgcn_fdot2(bc2((Tv).y), bc2((Hv).y), ACC, false); \
    ACC = __builtin_amdgcn_fdot2(bc2((Tv).z), bc2((Hv).z), ACC, false); \
    ACC = __builtin_amdgcn_fdot2(bc2((Tv).w), bc2((Hv).w), ACC, false); \
} while (0)

#define RED16(A) do { \
    A = dpp_add<0xB1>(A); A = dpp_add<0x4E>(A); \
    A = dpp_add<0x124>(A); A = dpp_add<0x128>(A); \
} while (0)

// Round 14: r13 proved byte-halving doesn't help -> weight stream is
// LATENCY-exposed (lockstep waves stall on vmcnt together), with LDS h-reads
// (~750cyc) and VALU (~850cyc) co-dominant. Fixes: (1) half of W resident in
// LDS (ds latency trivially hidden; DS+VMEM pipes run concurrently),
// (2) h in fp16 (halves LDS h-traffic; contraction bounds the noise -- fp16 W
// left absmax bit-identical twice), (3) v_dot2_f32_f16 halves FMA issue.
__global__ __launch_bounds__(NTHR)
void rnn_persist(
    const float* __restrict__ x,      // [B, T, 1]
    const float* __restrict__ W_ih,   // [256, 1]
    const uint4* __restrict__ wq,     // packed fp16 W_hh (d_ws)
    const float* __restrict__ b_ih,   // [256]
    const float* __restrict__ b_hh,   // [256]
    const float* __restrict__ W_out,  // [1, 256]
    const float* __restrict__ b_out,  // [1]
    float* __restrict__ y)            // [B, T, 1]
{
    // W rows 0,1 of each thread's 4-row slice: resident in LDS (64 KB)
    __shared__ uint4 s_w[4096];
    __shared__ float s_x[TT];
    // h as fp16, 16 chunks of 16 halfs, chunk stride 24 ushorts (48 B,
    // 16B-aligned; chunk bases 2-way bank-aliased at worst = ~free)
    __shared__ __align__(16) unsigned short s_hh[2][16 * 24];
    __shared__ float s_part[2][16];

    const int tid  = threadIdx.x;
    const int c3   = tid & 15;
    const int rg   = tid >> 4;
    const int lane = tid & 63;
    const int wv   = tid >> 6;
    const int b    = blockIdx.x;

    for (int k = tid; k < TT; k += NTHR) s_x[k] = x[(size_t)b * TT + k];

    // copy W-LDS half: LDS uint4 j=(wv*4+i)*64+lane (i=0..3) <- global
    // uint4 g=(wv*8+i)*64+lane = j + (j>>8)*256
    for (int j = tid; j < 4096; j += NTHR)
        s_w[j] = wq[j + ((j >> 8) << 8)];

    // zero h buffers (fp16 zero = 0x0000)
    if (tid < 768) (&s_hh[0][0])[tid] = 0;

    const int   myrow = 4 * rg + (c3 & 3);
    const float wih   = W_ih[myrow];
    const float bias  = b_ih[myrow] + b_hh[myrow];
    const float wo_my = W_out[myrow];
    const float bout  = b_out[0];

    const uint4* lbase = s_w + (wv * 4) * 64 + lane;           // LDS W rows 0,1
    const uint4* sbase = wq + (size_t)(wv * 8 + 4) * 64 + lane; // stream rows 2,3
    const int hwidx  = 24 * (myrow >> 4) + (myrow & 15);        // h write (ushort)
    const int hrbase = 24 * c3;                                 // h read (ushort)

    __syncthreads();

    int p = 0;
    float* yrow = y + (size_t)b * TT;

    for (int step = 0; step <= TT; ++step) {
        // finalize y_{step-1}: rotating wave sums the 16 per-wave partials
        if (step >= 1 && wv == ((step - 1) & 15)) {
            float pp = s_part[(step - 1) & 1][lane & 15];
            pp = dpp_add<0xB1>(pp);
            pp = dpp_add<0x4E>(pp);
            pp = dpp_add<0x124>(pp);
            pp = dpp_add<0x128>(pp);
            if (lane == 0) yrow[step - 1] = pp + bout;
        }
        if (step == TT) break;

        // streamed W (rows 2,3): issue early, consumed late in the step
        const uint4 T0 = sbase[0];
        const uint4 T1 = sbase[64];
        const uint4 T2 = sbase[128];
        const uint4 T3 = sbase[192];

        // h (fp16): 2 x ds_read_b128 = 16 halfs
        const uint4 H0 = *(const uint4*)&s_hh[p][hrbase];
        const uint4 H1 = *(const uint4*)&s_hh[p][hrbase + 8];

        // LDS W (rows 0,1)
        const uint4 L0 = lbase[0];
        const uint4 L1 = lbase[64];
        const uint4 L2 = lbase[128];
        const uint4 L3 = lbase[192];

        const float xt = s_x[step];

        float acc0 = 0.0f, acc1 = 0.0f, acc2 = 0.0f, acc3 = 0.0f;
        DOT4(acc0, L0, H0); DOT4(acc0, L1, H1);
        DOT4(acc1, L2, H0); DOT4(acc1, L3, H1);
        DOT4(acc2, T0, H0); DOT4(acc2, T1, H1);
        DOT4(acc3, T2, H0); DOT4(acc3, T3, H1);

        RED16(acc0); RED16(acc1); RED16(acc2); RED16(acc3);

        float s01 = (c3 & 1) ? acc1 : acc0;
        float s23 = (c3 & 1) ? acc3 : acc2;
        float dot = (c3 & 2) ? s23 : s01;
        float hn  = tanh_fast(fmaf(xt, wih, bias) + dot);

        if ((c3 & 12) == 0) {   // c3 < 4: write h as fp16
            _Float16 hh = (_Float16)hn;
            unsigned short us;
            __builtin_memcpy(&us, &hh, 2);
            s_hh[p ^ 1][hwidx] = us;
        }

        float pv = ((c3 & 12) == 0) ? hn * wo_my : 0.0f;
        pv = dpp_add<0xB1>(pv);
        pv = dpp_add<0x4E>(pv);
        pv = dpp_add<0x124>(pv);
        pv = dpp_add<0x128>(pv);
        pv = dpp_add<0x142>(pv);   // row_bcast15
        pv = dpp_add<0x143>(pv);   // row_bcast31 -> lane63 holds full sum
        if (lane == 63) s_part[step & 1][wv] = pv;

        __syncthreads();
        p ^= 1;
    }
}

extern "C" void kernel_launch(void* const* d_in, const int* in_sizes, int n_in,
                              void* d_out, int out_size, void* d_ws, size_t ws_size,
                              hipStream_t stream) {
    const float* x     = (const float*)d_in[0];
    const float* W_ih  = (const float*)d_in[1];
    const float* W_hh  = (const float*)d_in[2];
    const float* b_ih  = (const float*)d_in[3];
    const float* b_hh  = (const float*)d_in[4];
    const float* W_out = (const float*)d_in[5];
    const float* b_out = (const float*)d_in[6];
    float* y = (float*)d_out;
    unsigned int* wpk = (unsigned int*)d_ws;   // 32768 u32 = 128 KB

    hipLaunchKernelGGL(pack_w, dim3(128), dim3(256), 0, stream, W_hh, wpk);
    hipLaunchKernelGGL(rnn_persist, dim3(NB), dim3(NTHR), 0, stream,
                       x, W_ih, (const uint4*)wpk, b_ih, b_hh, W_out, b_out, y);
}